// Round 14
// baseline (223.548 us; speedup 1.0000x reference)
//
#include <hip/hip_runtime.h>
#include <hip/hip_bf16.h>

#define S_ 4096
#define D_ 1024
#define H_ 16
#define DK_ 64
#define DV_ 64

typedef short bf16x8 __attribute__((ext_vector_type(8)));
typedef short bf16x4 __attribute__((ext_vector_type(4)));
typedef float floatx4 __attribute__((ext_vector_type(4)));
using bf16 = __hip_bfloat16;

#define MFMA16(a, b, c) __builtin_amdgcn_mfma_f32_16x16x32_bf16(a, b, c, 0, 0, 0)

#if __has_builtin(__builtin_amdgcn_exp2f)
#define EXP2(x) __builtin_amdgcn_exp2f(x)
#else
#define EXP2(x) exp2f(x)
#endif

// async global->LDS, 16B per lane. lds ptr wave-uniform; HW adds lane*16.
__device__ __forceinline__ void stage16(const void* g, void* l) {
    __builtin_amdgcn_global_load_lds(
        (const __attribute__((address_space(1))) void*)g,
        (__attribute__((address_space(3))) void*)l, 16, 0, 0);
}

// bf16x8 fragment from a swizzled [rows][64] LDS tile (row = 8 chunks of 16B).
__device__ __forceinline__ bf16x8 ldsfrag(const bf16* base, int row, int chunk) {
    return *(const bf16x8*)(base + row * 64 + (((chunk ^ (row & 7))) << 3));
}
// bf16x8 fragment from a swizzled [rows][32] LDS tile (row = 4 chunks of 16B).
__device__ __forceinline__ bf16x8 ldsfrag32(const bf16* base, int row, int chunk) {
    return *(const bf16x8*)(base + row * 32 + (((chunk ^ (row & 3))) << 3));
}

__device__ __forceinline__ unsigned short bfbits(float f) {
    union { bf16 h; unsigned short u; } c; c.h = __float2bfloat16(f); return c.u;
}
__device__ __forceinline__ float bf2f(bf16 h) { return __bfloat162float(h); }
// RNE pair pack (epilogue use — precision-preserving)
__device__ __forceinline__ unsigned int pkrne(float lo, float hi) {
    return (unsigned int)bfbits(lo) | ((unsigned int)bfbits(hi) << 16);
}

// TRUNCATING pack of two fp32 -> bf16x2 in ONE v_perm_b32.
// Safe for softmax P (uniform trunc bias cancels in sum-normalization) and
// for already-normalized outputs (error < 1 ulp bf16 = within budget).
__device__ __forceinline__ unsigned int pktrunc(float lo, float hi) {
    union { float f; unsigned int u; } a, b;
    a.f = hi; b.f = lo;
    return __builtin_amdgcn_perm(a.u, b.u, 0x07060302u);
}

// counted-wait + fence + raw barrier (T4 pattern; rule #18 sched_barrier)
#define WAITCNT_BAR(N)                                        \
    do {                                                      \
        asm volatile("s_waitcnt vmcnt(" #N ")" ::: "memory"); \
        __builtin_amdgcn_sched_barrier(0);                    \
        __builtin_amdgcn_s_barrier();                         \
    } while (0)

// ---------------------------------------------------------------------------
// prep (merged): [0,2048) cvt_x | [2048,2816) tr_qkv | [2816,3072) tr_wc
// (R19 version: vectorized transpose stores)
// ---------------------------------------------------------------------------
__global__ __launch_bounds__(256)
void prep(const float* __restrict__ x, const float* __restrict__ Wq,
          const float* __restrict__ Wk, const float* __restrict__ Wv,
          const float* __restrict__ Wc,
          bf16* __restrict__ xb, bf16* __restrict__ Wt, bf16* __restrict__ Wct)
{
    __shared__ float ls[64][65];
    const int bx = blockIdx.x, t = threadIdx.x;

    if (bx < 2048) {                       // ---- x fp32 -> bf16
        int i = bx * 2048 + t * 8;
        float4 a = *(const float4*)(x + i);
        float4 b = *(const float4*)(x + i + 4);
        ushort4 lo, hi;
        lo.x = bfbits(a.x); lo.y = bfbits(a.y); lo.z = bfbits(a.z); lo.w = bfbits(a.w);
        hi.x = bfbits(b.x); hi.y = bfbits(b.y); hi.z = bfbits(b.z); hi.w = bfbits(b.w);
        *(ushort4*)(xb + i) = lo;
        *(ushort4*)(xb + i + 4) = hi;
        return;
    }
    if (bx < 2816) {                       // ---- Wq/Wk/Wv transpose+cvt (+scale on Wq)
        const int idx = bx - 2048;
        const int z = idx >> 4, which = z >> 4, h = z & 15;
        const float* s = (which == 0 ? Wq : which == 1 ? Wk : Wv) + (size_t)h * D_ * 64;
        bf16* d = Wt + ((size_t)which * 1024 + h * 64) * D_;
        const float scale = (which == 0) ? 0.125f * 1.44269504088896340736f : 1.0f;
        const int r0 = (idx & 15) * 64;
        {
            int r = t >> 2, cseg = (t & 3) * 16;
            const float* sp = s + (size_t)(r0 + r) * 64 + cseg;
            #pragma unroll
            for (int i = 0; i < 16; i += 4) {
                float4 v = *(const float4*)(sp + i);
                ls[r][cseg + i + 0] = v.x; ls[r][cseg + i + 1] = v.y;
                ls[r][cseg + i + 2] = v.z; ls[r][cseg + i + 3] = v.w;
            }
        }
        __syncthreads();
        {
            int c = t >> 2, rseg = (t & 3) * 16;
            bf16* dp = d + (size_t)c * D_ + r0 + rseg;
            unsigned int u[8];
            #pragma unroll
            for (int i = 0; i < 8; i++)
                u[i] = pkrne(ls[rseg + 2 * i][c] * scale, ls[rseg + 2 * i + 1][c] * scale);
            uint4 o0, o1;
            o0.x = u[0]; o0.y = u[1]; o0.z = u[2]; o0.w = u[3];
            o1.x = u[4]; o1.y = u[5]; o1.z = u[6]; o1.w = u[7];
            *(uint4*)(dp)     = o0;
            *(uint4*)(dp + 8) = o1;
        }
        return;
    }
    {                                      // ---- Wc transpose+cvt
        const int idx = bx - 2816;
        const int r0 = (idx & 15) * 64, c0 = (idx >> 4) * 64;
        {
            int r = t >> 2, cseg = (t & 3) * 16;
            const float* sp = Wc + (size_t)(r0 + r) * D_ + c0 + cseg;
            #pragma unroll
            for (int i = 0; i < 16; i += 4) {
                float4 v = *(const float4*)(sp + i);
                ls[r][cseg + i + 0] = v.x; ls[r][cseg + i + 1] = v.y;
                ls[r][cseg + i + 2] = v.z; ls[r][cseg + i + 3] = v.w;
            }
        }
        __syncthreads();
        {
            int c = t >> 2, rseg = (t & 3) * 16;
            bf16* dp = Wct + (size_t)(c0 + c) * D_ + r0 + rseg;
            unsigned int u[8];
            #pragma unroll
            for (int i = 0; i < 8; i++)
                u[i] = pkrne(ls[rseg + 2 * i][c], ls[rseg + 2 * i + 1][c]);
            uint4 o0, o1;
            o0.x = u[0]; o0.y = u[1]; o0.z = u[2]; o0.w = u[3];
            o1.x = u[4]; o1.y = u[5]; o1.z = u[6]; o1.w = u[7];
            *(uint4*)(dp)     = o0;
            *(uint4*)(dp + 8) = o1;
        }
    }
}

// ---------------------------------------------------------------------------
// Kernel 1: fused QKV GEMM — R26: 256x256 tiles, BK=64, 512 threads (8
// waves, 2x4), LDS 128KB, 1 block/CU. Per-kt body = 64 MFMA/wave (vs 16 at
// 128²): the drain+barrier fraction drops ~4x, which the ledger says is
// qkv's cost (R20/R23 wins were exactly drain-amortization; m132 trap
// avoided since 1 block/CU is the intended big-tile regime — intra-wave ILP
// from 32 acc chains hides latency, not TLP). kts 32->16. Sync = proven
// R19/R20 pattern (syncthreads drain; stage-next after barrier). Fragment/
// swizzle = the proven [rows][64] ldsfrag machinery. Grid 16x12 = 192
// blocks (24/XCD via bijective swizzle; B-working-set 1MB L2-fits).
// acc[8][4] = 128 VGPR; waves_per_eu(2) -> 256 budget, no spill expected.
// ---------------------------------------------------------------------------
__global__ __attribute__((amdgpu_waves_per_eu(2))) __launch_bounds__(512)
void qkv_gemm(const bf16* __restrict__ xb, const bf16* __restrict__ Wt,
              bf16* __restrict__ Qb, bf16* __restrict__ Kb, bf16* __restrict__ Vtb)
{
    const int fid = blockIdx.x + 16 * blockIdx.y;      // x fastest in dispatch
    const int lin = (fid & 7) * 24 + (fid >> 3);       // bijective: 192 = 8*24
    const int m0 = (lin & 15) * 256;
    const int n0 = (lin >> 4) * 256;
    __shared__ __align__(16) bf16 xa[2][256 * 64];     // 32 KB/buf
    __shared__ __align__(16) bf16 wb2[2][256 * 64];    // 32 KB/buf

    const int t = threadIdx.x, lane = t & 63, w = t >> 6;
    const int l15 = lane & 15, quad = lane >> 4;
    const int wr = w >> 2, wc = w & 3;                 // wave -> (2 x 4) grid

    // 4+4 = 8 stage16 per thread per tile; [rows][64] swizzled dest
    // (idx = j*512+t -> row=idx>>3, slot=idx&7; slot holds chunk ch=slot^(row&7))
    auto stage_ab = [&](int buf, int kk) {
        #pragma unroll
        for (int j = 0; j < 4; j++) {
            int idx = j * 512 + t;
            int r = idx >> 3, c = idx & 7;
            int ch = c ^ (r & 7);
            stage16((const char*)xb + ((size_t)(m0 + r) * D_ + kk + ch * 8) * 2,
                    (char*)&xa[buf][0] + (j * 8 + w) * 1024);
        }
        #pragma unroll
        for (int j = 0; j < 4; j++) {
            int idx = j * 512 + t;
            int r = idx >> 3, c = idx & 7;
            int ch = c ^ (r & 7);
            stage16((const char*)Wt + ((size_t)(n0 + r) * D_ + kk + ch * 8) * 2,
                    (char*)&wb2[buf][0] + (j * 8 + w) * 1024);
        }
    };

    const floatx4 fz = {0.f, 0.f, 0.f, 0.f};
    floatx4 acc[8][4];
    #pragma unroll
    for (int mt = 0; mt < 8; mt++)
        #pragma unroll
        for (int nt = 0; nt < 4; nt++) acc[mt][nt] = fz;

    const int which = n0 >> 10;            // uniform per block (256 | 1024)

    stage_ab(0, 0);
    if (which != 2) {
        // ---- Q/K: swapped operands -> C^T regs ----
        #pragma unroll 1
        for (int kt = 0; kt < 16; kt++) {
            const int cur = kt & 1;
            __syncthreads();
            if (kt < 15) stage_ab(cur ^ 1, (kt + 1) * 64);
            #pragma unroll
            for (int ks = 0; ks < 2; ks++) {
                bf16x8 b[4];
                #pragma unroll
                for (int nt = 0; nt < 4; nt++)
                    b[nt] = ldsfrag(&wb2[cur][0], wc * 64 + nt * 16 + l15, ks * 4 + quad);
                #pragma unroll
                for (int mt = 0; mt < 8; mt++) {
                    bf16x8 a = ldsfrag(&xa[cur][0], wr * 128 + mt * 16 + l15, ks * 4 + quad);
                    #pragma unroll
                    for (int nt = 0; nt < 4; nt++)
                        acc[mt][nt] = MFMA16(b[nt], a, acc[mt][nt]);   // C^T
                }
            }
        }
        // epilogue: lane holds s = col index, n = row index of C^T ->
        // 4 consecutive output cols (n-quad) per uint2
        bf16* base = (which == 0) ? Qb : Kb;
        #pragma unroll
        for (int nt = 0; nt < 4; nt++) {
            int n  = n0 + wc * 64 + nt * 16 + quad * 4;
            int hh = (n >> 6) & 15, col = n & 63;
            #pragma unroll
            for (int mt = 0; mt < 8; mt++) {
                int s = m0 + wr * 128 + mt * 16 + l15;
                uint2 o;
                o.x = pkrne(acc[mt][nt][0], acc[mt][nt][1]);
                o.y = pkrne(acc[mt][nt][2], acc[mt][nt][3]);
                *(uint2*)(base + ((size_t)hh * S_ + s) * 64 + col) = o;
            }
        }
    } else {
        // ---- V: normal orientation -> reg-quad = 4 consecutive s ----
        #pragma unroll 1
        for (int kt = 0; kt < 16; kt++) {
            const int cur = kt & 1;
            __syncthreads();
            if (kt < 15) stage_ab(cur ^ 1, (kt + 1) * 64);
            #pragma unroll
            for (int ks = 0; ks < 2; ks++) {
                bf16x8 b[4];
                #pragma unroll
                for (int nt = 0; nt < 4; nt++)
                    b[nt] = ldsfrag(&wb2[cur][0], wc * 64 + nt * 16 + l15, ks * 4 + quad);
                #pragma unroll
                for (int mt = 0; mt < 8; mt++) {
                    bf16x8 a = ldsfrag(&xa[cur][0], wr * 128 + mt * 16 + l15, ks * 4 + quad);
                    #pragma unroll
                    for (int nt = 0; nt < 4; nt++)
                        acc[mt][nt] = MFMA16(a, b[nt], acc[mt][nt]);
                }
            }
        }
        #pragma unroll
        for (int nt = 0; nt < 4; nt++) {
            int n = n0 + wc * 64 + nt * 16 + l15;
            int hh = (n >> 6) & 15, col = n & 63;
            #pragma unroll
            for (int mt = 0; mt < 8; mt++) {
                int s = m0 + wr * 128 + mt * 16 + quad * 4;
                uint2 o;
                o.x = pkrne(acc[mt][nt][0], acc[mt][nt][1]);
                o.y = pkrne(acc[mt][nt][2], acc[mt][nt][3]);
                *(uint2*)(Vtb + ((size_t)hh * 64 + col) * S_ + s) = o;
            }
        }
    }
}

// ---------------------------------------------------------------------------
// Kernel 2: attention. (R17/R19/R23 champion version exactly — 83.2-83.9 µs)
// ---------------------------------------------------------------------------
template<int NKT, bool FULL>
__global__ __attribute__((amdgpu_waves_per_eu(2))) __launch_bounds__(256)
void attn(const bf16* __restrict__ Qb, const bf16* __restrict__ Kb,
          const bf16* __restrict__ Vtb, bf16* __restrict__ Cat,
          bf16* __restrict__ Opart, float* __restrict__ lpart)
{
    // ---- XCD-aware bijective swizzle (x fastest in dispatch linearization)
    const int fid = blockIdx.x + 16 * (blockIdx.y + 16 * blockIdx.z);
    const int xcd = fid & 7, r = fid >> 3;
    const int hz  = (r >> 4) * 8 + xcd;
    const int m0   = (r & 15) * 256;
    const int h    = hz & 15;
    const int half = hz >> 4;
    const int keybase = half * (NKT * 64);

    __shared__ __align__(16) bf16 ka[2][64 * 64];   // 8 KB/buf, swizzled [key][dk]
    __shared__ __align__(16) bf16 vt[2][64 * 64];   // 8 KB/buf, swizzled [dv][key]

    const int t = threadIdx.x, lane = t & 63, w = t >> 6;
    const int l15 = lane & 15, quad = lane >> 4;

    auto stage_kv = [&](int buf, int key0) {
        const char* kg = (const char*)(Kb + ((size_t)h * S_ + key0) * 64);
        #pragma unroll
        for (int j = 0; j < 2; j++) {
            int c = (j * 4 + w) * 64 + lane;
            int row = c >> 3, ch = (c & 7) ^ (row & 7);
            stage16(kg + row * 128 + ch * 16, (char*)&ka[buf][0] + (j * 4 + w) * 1024);
        }
        const char* vg = (const char*)(Vtb + (size_t)h * 64 * S_ + key0);
        #pragma unroll
        for (int j = 0; j < 2; j++) {
            int c = (j * 4 + w) * 64 + lane;
            int row = c >> 3, ch = (c & 7) ^ (row & 7);
            stage16(vg + (size_t)row * (S_ * 2) + ch * 16, (char*)&vt[buf][0] + (j * 4 + w) * 1024);
        }
    };

    // Q fragments, loop-invariant, straight from global (B-side of K·Qᵀ).
    // Wave owns q-rows [m0 + w*64, m0 + w*64 + 64).
    bf16x8 qf[4][2];
    #pragma unroll
    for (int nq = 0; nq < 4; nq++)
        #pragma unroll
        for (int ks = 0; ks < 2; ks++)
            qf[nq][ks] = *(const bf16x8*)(Qb +
                ((size_t)h * S_ + m0 + w * 64 + nq * 16 + l15) * 64 + ks * 32 + quad * 8);

    // all-ones bf16 A fragment for row-sum MFMA
    bf16x8 ones8;
    #pragma unroll
    for (int i = 0; i < 8; i++) ones8[i] = (short)0x3F80;

    const floatx4 fz = {0.f, 0.f, 0.f, 0.f};
    floatx4 acc[4][4];          // acc[nq][nt]: Oᵀ[dv=nt*16+quad*4+r][q=l15 of nq-tile]
    floatx4 rsa[4];             // rsa[nq][r] all == rowsum for q=l15 of nq-tile
    #pragma unroll
    for (int nq = 0; nq < 4; nq++) {
        rsa[nq] = fz;
        #pragma unroll
        for (int nt = 0; nt < 4; nt++) acc[nq][nt] = fz;
    }

    stage_kv(0, keybase);
    __syncthreads();

    #pragma unroll 1
    for (int kt = 0; kt < NKT; kt++) {
        const int cur = kt & 1;
        if (kt + 1 < NKT) stage_kv(cur ^ 1, keybase + (kt + 1) * 64);

        // Sᵀ[key][q] = K·Qᵀ, exp2 + truncating pack, mk-by-mk to bound liveness
        union bf4u { bf16x4 v; unsigned int u[2]; };
        bf4u pf[4][4];
        #pragma unroll
        for (int mk = 0; mk < 4; mk++) {
            bf16x8 a0 = ldsfrag(&ka[cur][0], mk * 16 + l15, quad);
            bf16x8 a1 = ldsfrag(&ka[cur][0], mk * 16 + l15, 4 + quad);
            floatx4 s[4];
            #pragma unroll
            for (int nq = 0; nq < 4; nq++) s[nq] = fz;
            __builtin_amdgcn_s_setprio(1);
            #pragma unroll
            for (int nq = 0; nq < 4; nq++) s[nq] = MFMA16(a0, qf[nq][0], s[nq]);
            #pragma unroll
            for (int nq = 0; nq < 4; nq++) s[nq] = MFMA16(a1, qf[nq][1], s[nq]);
            __builtin_amdgcn_s_setprio(0);
            #pragma unroll
            for (int nq = 0; nq < 4; nq++) {
                float p0 = EXP2(s[nq][0]);
                float p1 = EXP2(s[nq][1]);
                float p2 = EXP2(s[nq][2]);
                float p3 = EXP2(s[nq][3]);
                pf[mk][nq].u[0] = pktrunc(p0, p1);
                pf[mk][nq].u[1] = pktrunc(p2, p3);
            }
        }

        // Oᵀ += Vᵀ·Pᵀ : per pair p of 16-key groups (32 keys per MFMA);
        // rowsums ride the MFMA pipe via ones-A.
        #pragma unroll
        for (int p = 0; p < 2; p++) {
            union { bf16x8 v8; bf16x4 v4[2]; } b8[4];
            #pragma unroll
            for (int nq = 0; nq < 4; nq++) {
                b8[nq].v4[0] = pf[2 * p + 0][nq].v;
                b8[nq].v4[1] = pf[2 * p + 1][nq].v;
            }
            __builtin_amdgcn_s_setprio(1);
            #pragma unroll
            for (int nq = 0; nq < 4; nq++)
                rsa[nq] = MFMA16(ones8, b8[nq].v8, rsa[nq]);
            __builtin_amdgcn_s_setprio(0);
            #pragma unroll
            for (int nt = 0; nt < 4; nt++) {
                const char* vb = (const char*)&vt[cur][0]
                               + (nt * 16 + l15) * 128 + (quad & 1) * 8;
                const int r7 = l15 & 7;            // row&7 for swizzle
                union { bf16x8 v8; bf16x4 v4[2]; } a8;
                a8.v4[0] = *(const bf16x4*)(vb + (((4 * p +     (quad >> 1)) ^ r7) << 4));
                a8.v4[1] = *(const bf16x4*)(vb + (((4 * p + 2 + (quad >> 1)) ^ r7) << 4));
                __builtin_amdgcn_s_setprio(1);
                #pragma unroll
                for (int nq = 0; nq < 4; nq++)
                    acc[nq][nt] = MFMA16(a8.v8, b8[nq].v8, acc[nq][nt]);
                __builtin_amdgcn_s_setprio(0);
            }
        }
        __syncthreads();   // staging(next) landed; all waves done with cur
    }

    if (FULL) {
        #pragma unroll
        for (int nq = 0; nq < 4; nq++) {
            float inv = 1.0f / rsa[nq][0];
            int q = m0 + w * 64 + nq * 16 + l15;
            #pragma unroll
            for (int nt = 0; nt < 4; nt++) {
                uint2 o;
                o.x = pktrunc(acc[nq][nt][0] * inv, acc[nq][nt][1] * inv);
                o.y = pktrunc(acc[nq][nt][2] * inv, acc[nq][nt][3] * inv);
                *(uint2*)(Cat + (size_t)q * (H_ * DV_) + h * 64 + nt * 16 + quad * 4) = o;
            }
        }
    } else {
        const size_t plane = (size_t)(half * H_ + h) * S_;
        #pragma unroll
        for (int nq = 0; nq < 4; nq++) {
            int q = m0 + w * 64 + nq * 16 + l15;
            #pragma unroll
            for (int nt = 0; nt < 4; nt++) {
                uint2 o;
                o.x = pktrunc(acc[nq][nt][0], acc[nq][nt][1]);
                o.y = pktrunc(acc[nq][nt][2], acc[nq][nt][3]);
                *(uint2*)(Opart + (plane + q) * 64 + nt * 16 + quad * 4) = o;
            }
            if (quad == 0) lpart[plane + q] = rsa[nq][0];
        }
    }
}

// ---------------------------------------------------------------------------
// Kernel 2b: combine NS bf16 key-split partials -> Cat bf16
// ---------------------------------------------------------------------------
template<int NS>
__global__ __launch_bounds__(256)
void combineN(const bf16* __restrict__ Opart, const float* __restrict__ lpart,
              bf16* __restrict__ Cat)
{
    const int h = blockIdx.y;
    const int off = (blockIdx.x * 256 + threadIdx.x) * 8;   // within [S*64]
    const int s = off >> 6, dv = off & 63;
    float a[8] = {0.f, 0.f, 0.f, 0.f, 0.f, 0.f, 0.f, 0.f};
    float l = 0.f;
    #pragma unroll
    for (int p = 0; p < NS; p++) {
        union { bf16x8 v; bf16 e[8]; } o;
        o.v = *(const bf16x8*)(Opart + (size_t)(p * H_ + h) * S_ * 64 + off);
        #pragma unroll
        for (int i = 0; i < 8; i++) a[i] += bf2f(o.e[i]);
        l += lpart[(size_t)(p * H_ + h) * S_ + s];
    }
    float inv = 1.0f / l;
    uint4 o;
    o.x = pktrunc(a[0] * inv, a[1] * inv);
    o.y = pktrunc(a[2] * inv, a[3] * inv);
    o.z = pktrunc(a[4] * inv, a[5] * inv);
    o.w = pktrunc(a[6] * inv, a[7] * inv);
    *(uint4*)(Cat + (size_t)s * (H_ * DV_) + h * 64 + dv) = o;
}

// ---------------------------------------------------------------------------
// Kernel 3: output projection, 128x64 tiles, BK=64, 3-deep counted-vmcnt
// ring (R23 version — measured in the 219.3 champion).
// ---------------------------------------------------------------------------
__global__ __launch_bounds__(256)
void out_proj(const bf16* __restrict__ Cat, const bf16* __restrict__ Wct,
              const float* __restrict__ bc, float* __restrict__ out)
{
    const int fid = blockIdx.x + 32 * blockIdx.y;      // x fastest
    const int lin = (fid & 7) * 64 + (fid >> 3);       // bijective: 512 = 8*64
    const int m0 = (lin & 31) * 128;
    const int n0 = (lin >> 5) * 64;
    __shared__ __align__(16) bf16 ca[3][128 * 64];   // 16 KB/buf
    __shared__ __align__(16) bf16 wb2[3][64 * 64];   // 8 KB/buf

    const int t = threadIdx.x, lane = t & 63, w = t >> 6;
    const int l15 = lane & 15, quad = lane >> 4;

    // 4+2 = 6 stage16 per thread per tile
    auto stage_ab = [&](int buf, int kk) {
        #pragma unroll
        for (int j = 0; j < 4; j++) {
            int idx = j * 256 + t;
            int r = idx >> 3, c = idx & 7;
            int ch = c ^ (r & 7);
            stage16((const char*)Cat + ((size_t)(m0 + r) * D_ + kk + ch * 8) * 2,
                    (char*)&ca[buf][0] + (j * 4 + w) * 1024);
        }
        #pragma unroll
        for (int j = 0; j < 2; j++) {
            int idx = j * 256 + t;
            int r = idx >> 3, c = idx & 7;
            int ch = c ^ (r & 7);
            stage16((const char*)Wct + ((size_t)(n0 + r) * D_ + kk + ch * 8) * 2,
                    (char*)&wb2[buf][0] + (j * 4 + w) * 1024);
        }
    };

    const floatx4 fz = {0.f, 0.f, 0.f, 0.f};
    floatx4 acc[2][4];
    #pragma unroll
    for (int mt = 0; mt < 2; mt++)
        #pragma unroll
        for (int nt = 0; nt < 4; nt++) acc[mt][nt] = fz;

    // prologue: 2 tiles in flight, counted wait for tile 0 only
    stage_ab(0, 0);
    stage_ab(1, 64);
    WAITCNT_BAR(6);

    #pragma unroll 1
    for (int kt = 0; kt < 16; kt++) {
        const int cur = kt % 3;
        if (kt + 2 < 16) stage_ab((kt + 2) % 3, (kt + 2) * 64);
        #pragma unroll
        for (int ks = 0; ks < 2; ks++) {
            bf16x8 a0 = ldsfrag(&ca[cur][0], w * 32 + l15,      ks * 4 + quad);
            bf16x8 a1 = ldsfrag(&ca[cur][0], w * 32 + 16 + l15, ks * 4 + quad);
            #pragma unroll
            for (int nt = 0; nt < 4; nt++) {
                bf16x8 b = ldsfrag(&wb2[cur][0], nt * 16 + l15, ks * 4 + quad);
                acc[0][nt] = MFMA16(a0, b, acc[0][nt]);
                acc[1][nt] = MFMA16(a1, b, acc[1][nt]);
            }
        }
        if (kt + 1 < 16) {
            if (kt + 2 < 16) { WAITCNT_BAR(6); } else { WAITCNT_BAR(0); }
        }
    }

    #pragma unroll
    for (int nt = 0; nt < 4; nt++) {
        int col = n0 + nt * 16 + l15;
        float bias = bc[col];
        #pragma unroll
        for (int mt = 0; mt < 2; mt++)
            #pragma unroll
            for (int r = 0; r < 4; r++) {
                int row = m0 + w * 32 + mt * 16 + quad * 4 + r;
                out[(size_t)row * D_ + col] = acc[mt][nt][r] + bias;
            }
    }
}

extern "C" void kernel_launch(void* const* d_in, const int* in_sizes, int n_in,
                              void* d_out, int out_size, void* d_ws, size_t ws_size,
                              hipStream_t stream)
{
    const float* x  = (const float*)d_in[0];
    const float* Wq = (const float*)d_in[1];
    const float* Wk = (const float*)d_in[2];
    const float* Wv = (const float*)d_in[3];
    const float* Wc = (const float*)d_in[4];
    const float* bc = (const float*)d_in[5];
    float* out = (float*)d_out;

    bf16* xb  = (bf16*)d_ws;                          // [S][D] 8MB, aliased as Cat
    bf16* Cat = xb;
    bf16* Wt  = xb  + (size_t)S_ * D_;                // [3072][1024] 6MB
    bf16* Wct = Wt  + (size_t)3 * H_ * 64 * D_;       // [1024][1024] 2MB
    bf16* Qb  = Wct + (size_t)D_ * H_ * DV_;          // [H][S][64]  8MB
    bf16* Kb  = Qb  + (size_t)H_ * S_ * 64;           // [H][S][64]  8MB
    bf16* Vtb = Kb  + (size_t)H_ * S_ * 64;           // [H][64][S]  8MB
    bf16* Opart = Vtb + (size_t)H_ * 64 * S_;         // [NS][H][S][64] bf16, NS*8MB

    // lpart sits after however many Opart planes the chosen split uses
    float* lpart4 = (float*)(Opart + (size_t)4 * H_ * S_ * 64);  // [4][H][S]
    float* lpart2 = (float*)(Opart + (size_t)2 * H_ * S_ * 64);  // [2][H][S]
    const size_t need4 = (size_t)((char*)(lpart4 + (size_t)4 * H_ * S_) - (char*)d_ws);
    const size_t need2 = (size_t)((char*)(lpart2 + (size_t)2 * H_ * S_) - (char*)d_ws);

    prep<<<dim3(3072), 256, 0, stream>>>(x, Wq, Wk, Wv, Wc, xb, Wt, Wct);
    qkv_gemm<<<dim3(16, 12), 512, 0, stream>>>(xb, Wt, Qb, Kb, Vtb);

    if (ws_size >= need4) {
        attn<16, false><<<dim3(16, 16, 4), 256, 0, stream>>>(
            Qb, Kb, Vtb, Cat, Opart, lpart4);
        combineN<4><<<dim3(S_ * 64 / 2048, H_), 256, 0, stream>>>(Opart, lpart4, Cat);
    } else if (ws_size >= need2) {
        attn<32, false><<<dim3(16, 16, 2), 256, 0, stream>>>(
            Qb, Kb, Vtb, Cat, Opart, lpart2);
        combineN<2><<<dim3(S_ * 64 / 2048, H_), 256, 0, stream>>>(Opart, lpart2, Cat);
    } else {
        attn<64, true><<<dim3(16, 16, 1), 256, 0, stream>>>(
            Qb, Kb, Vtb, Cat, Opart, lpart2);
    }

    out_proj<<<dim3(S_ / 128, D_ / 64), 256, 0, stream>>>(Cat, Wct, bc, out);
}

// Round 15
// 218.818 us; speedup vs baseline: 1.0216x; 1.0216x over previous
//
#include <hip/hip_runtime.h>
#include <hip/hip_bf16.h>

#define S_ 4096
#define D_ 1024
#define H_ 16
#define DK_ 64
#define DV_ 64

typedef short bf16x8 __attribute__((ext_vector_type(8)));
typedef short bf16x4 __attribute__((ext_vector_type(4)));
typedef float floatx4 __attribute__((ext_vector_type(4)));
using bf16 = __hip_bfloat16;

#define MFMA16(a, b, c) __builtin_amdgcn_mfma_f32_16x16x32_bf16(a, b, c, 0, 0, 0)

#if __has_builtin(__builtin_amdgcn_exp2f)
#define EXP2(x) __builtin_amdgcn_exp2f(x)
#else
#define EXP2(x) exp2f(x)
#endif

// async global->LDS, 16B per lane. lds ptr wave-uniform; HW adds lane*16.
__device__ __forceinline__ void stage16(const void* g, void* l) {
    __builtin_amdgcn_global_load_lds(
        (const __attribute__((address_space(1))) void*)g,
        (__attribute__((address_space(3))) void*)l, 16, 0, 0);
}

// bf16x8 fragment from a swizzled [rows][64] LDS tile (row = 8 chunks of 16B).
__device__ __forceinline__ bf16x8 ldsfrag(const bf16* base, int row, int chunk) {
    return *(const bf16x8*)(base + row * 64 + (((chunk ^ (row & 7))) << 3));
}
// bf16x8 fragment from a swizzled [rows][32] LDS tile (row = 4 chunks of 16B).
__device__ __forceinline__ bf16x8 ldsfrag32(const bf16* base, int row, int chunk) {
    return *(const bf16x8*)(base + row * 32 + (((chunk ^ (row & 3))) << 3));
}

__device__ __forceinline__ unsigned short bfbits(float f) {
    union { bf16 h; unsigned short u; } c; c.h = __float2bfloat16(f); return c.u;
}
__device__ __forceinline__ float bf2f(bf16 h) { return __bfloat162float(h); }
// RNE pair pack (epilogue use — precision-preserving)
__device__ __forceinline__ unsigned int pkrne(float lo, float hi) {
    return (unsigned int)bfbits(lo) | ((unsigned int)bfbits(hi) << 16);
}

// TRUNCATING pack of two fp32 -> bf16x2 in ONE v_perm_b32.
// Safe for softmax P (uniform trunc bias cancels in sum-normalization) and
// for already-normalized outputs (error < 1 ulp bf16 = within budget).
__device__ __forceinline__ unsigned int pktrunc(float lo, float hi) {
    union { float f; unsigned int u; } a, b;
    a.f = hi; b.f = lo;
    return __builtin_amdgcn_perm(a.u, b.u, 0x07060302u);
}

// counted-wait + fence + raw barrier (T4 pattern; rule #18 sched_barrier)
#define WAITCNT_BAR(N)                                        \
    do {                                                      \
        asm volatile("s_waitcnt vmcnt(" #N ")" ::: "memory"); \
        __builtin_amdgcn_sched_barrier(0);                    \
        __builtin_amdgcn_s_barrier();                         \
    } while (0)

// ---------------------------------------------------------------------------
// prep (merged): [0,2048) cvt_x | [2048,2816) tr_qkv | [2816,3072) tr_wc
// (R19 version: vectorized transpose stores)
// ---------------------------------------------------------------------------
__global__ __launch_bounds__(256)
void prep(const float* __restrict__ x, const float* __restrict__ Wq,
          const float* __restrict__ Wk, const float* __restrict__ Wv,
          const float* __restrict__ Wc,
          bf16* __restrict__ xb, bf16* __restrict__ Wt, bf16* __restrict__ Wct)
{
    __shared__ float ls[64][65];
    const int bx = blockIdx.x, t = threadIdx.x;

    if (bx < 2048) {                       // ---- x fp32 -> bf16
        int i = bx * 2048 + t * 8;
        float4 a = *(const float4*)(x + i);
        float4 b = *(const float4*)(x + i + 4);
        ushort4 lo, hi;
        lo.x = bfbits(a.x); lo.y = bfbits(a.y); lo.z = bfbits(a.z); lo.w = bfbits(a.w);
        hi.x = bfbits(b.x); hi.y = bfbits(b.y); hi.z = bfbits(b.z); hi.w = bfbits(b.w);
        *(ushort4*)(xb + i) = lo;
        *(ushort4*)(xb + i + 4) = hi;
        return;
    }
    if (bx < 2816) {                       // ---- Wq/Wk/Wv transpose+cvt (+scale on Wq)
        const int idx = bx - 2048;
        const int z = idx >> 4, which = z >> 4, h = z & 15;
        const float* s = (which == 0 ? Wq : which == 1 ? Wk : Wv) + (size_t)h * D_ * 64;
        bf16* d = Wt + ((size_t)which * 1024 + h * 64) * D_;
        const float scale = (which == 0) ? 0.125f * 1.44269504088896340736f : 1.0f;
        const int r0 = (idx & 15) * 64;
        {
            int r = t >> 2, cseg = (t & 3) * 16;
            const float* sp = s + (size_t)(r0 + r) * 64 + cseg;
            #pragma unroll
            for (int i = 0; i < 16; i += 4) {
                float4 v = *(const float4*)(sp + i);
                ls[r][cseg + i + 0] = v.x; ls[r][cseg + i + 1] = v.y;
                ls[r][cseg + i + 2] = v.z; ls[r][cseg + i + 3] = v.w;
            }
        }
        __syncthreads();
        {
            int c = t >> 2, rseg = (t & 3) * 16;
            bf16* dp = d + (size_t)c * D_ + r0 + rseg;
            unsigned int u[8];
            #pragma unroll
            for (int i = 0; i < 8; i++)
                u[i] = pkrne(ls[rseg + 2 * i][c] * scale, ls[rseg + 2 * i + 1][c] * scale);
            uint4 o0, o1;
            o0.x = u[0]; o0.y = u[1]; o0.z = u[2]; o0.w = u[3];
            o1.x = u[4]; o1.y = u[5]; o1.z = u[6]; o1.w = u[7];
            *(uint4*)(dp)     = o0;
            *(uint4*)(dp + 8) = o1;
        }
        return;
    }
    {                                      // ---- Wc transpose+cvt
        const int idx = bx - 2816;
        const int r0 = (idx & 15) * 64, c0 = (idx >> 4) * 64;
        {
            int r = t >> 2, cseg = (t & 3) * 16;
            const float* sp = Wc + (size_t)(r0 + r) * D_ + c0 + cseg;
            #pragma unroll
            for (int i = 0; i < 16; i += 4) {
                float4 v = *(const float4*)(sp + i);
                ls[r][cseg + i + 0] = v.x; ls[r][cseg + i + 1] = v.y;
                ls[r][cseg + i + 2] = v.z; ls[r][cseg + i + 3] = v.w;
            }
        }
        __syncthreads();
        {
            int c = t >> 2, rseg = (t & 3) * 16;
            bf16* dp = Wct + (size_t)(c0 + c) * D_ + r0 + rseg;
            unsigned int u[8];
            #pragma unroll
            for (int i = 0; i < 8; i++)
                u[i] = pkrne(ls[rseg + 2 * i][c], ls[rseg + 2 * i + 1][c]);
            uint4 o0, o1;
            o0.x = u[0]; o0.y = u[1]; o0.z = u[2]; o0.w = u[3];
            o1.x = u[4]; o1.y = u[5]; o1.z = u[6]; o1.w = u[7];
            *(uint4*)(dp)     = o0;
            *(uint4*)(dp + 8) = o1;
        }
    }
}

// ---------------------------------------------------------------------------
// Kernel 1: fused QKV GEMM, 128x128 tiles, BK=32, 3-deep counted-vmcnt ring
// (R23 champion version — measured 219.3/219.8. R26's 256²/BK=64 big-tile
// regressed +4µs: 192 blocks = 1/CU left 25% CUs idle and lost the ring.)
// ---------------------------------------------------------------------------
__global__ __launch_bounds__(256)
void qkv_gemm(const bf16* __restrict__ xb, const bf16* __restrict__ Wt,
              bf16* __restrict__ Qb, bf16* __restrict__ Kb, bf16* __restrict__ Vtb)
{
    const int fid = blockIdx.x + 32 * blockIdx.y;      // x fastest in dispatch
    const int lin = (fid & 7) * 96 + (fid >> 3);       // bijective: 768 = 8*96
    const int m0 = (lin & 31) * 128;
    const int n0 = (lin >> 5) * 128;
    __shared__ __align__(16) bf16 xa[3][128 * 32];    // 8 KB each buf
    __shared__ __align__(16) bf16 wb2[3][128 * 32];

    const int t = threadIdx.x, lane = t & 63, w = t >> 6;
    const int l15 = lane & 15, quad = lane >> 4;

    // 2+2 = 4 stage16 per thread per tile
    auto stage_ab = [&](int buf, int kk) {
        #pragma unroll
        for (int j = 0; j < 2; j++) {
            int row = j * 64 + (t >> 2);
            int ch  = (t & 3) ^ (row & 3);
            stage16((const char*)xb + ((size_t)(m0 + row) * D_ + kk) * 2 + ch * 16,
                    (char*)&xa[buf][0] + (j * 4 + w) * 1024);
        }
        #pragma unroll
        for (int j = 0; j < 2; j++) {
            int row = j * 64 + (t >> 2);
            int ch  = (t & 3) ^ (row & 3);
            stage16((const char*)Wt + ((size_t)(n0 + row) * D_ + kk) * 2 + ch * 16,
                    (char*)&wb2[buf][0] + (j * 4 + w) * 1024);
        }
    };

    const floatx4 fz = {0.f, 0.f, 0.f, 0.f};
    floatx4 acc[2][8];
    #pragma unroll
    for (int mt = 0; mt < 2; mt++)
        #pragma unroll
        for (int nt = 0; nt < 8; nt++) acc[mt][nt] = fz;

    const int which = n0 >> 10;            // uniform per block

    // prologue: 2 tiles in flight, counted wait for tile 0 only
    stage_ab(0, 0);
    stage_ab(1, 32);
    WAITCNT_BAR(4);

    if (which != 2) {
        // ---- Q/K: swapped operands -> C^T regs ----
        #pragma unroll 1
        for (int kt = 0; kt < 32; kt++) {
            const int cur = kt % 3;
            if (kt + 2 < 32) stage_ab((kt + 2) % 3, (kt + 2) * 32);
            bf16x8 a0 = ldsfrag32(&xa[cur][0], w * 32 + l15,      quad);
            bf16x8 a1 = ldsfrag32(&xa[cur][0], w * 32 + 16 + l15, quad);
            #pragma unroll
            for (int nt = 0; nt < 8; nt++) {
                bf16x8 b = ldsfrag32(&wb2[cur][0], nt * 16 + l15, quad);
                acc[0][nt] = MFMA16(b, a0, acc[0][nt]);   // C^T: rows=n, cols=m
                acc[1][nt] = MFMA16(b, a1, acc[1][nt]);
            }
            if (kt + 1 < 32) {
                if (kt + 2 < 32) { WAITCNT_BAR(4); } else { WAITCNT_BAR(0); }
            }
        }
        // epilogue: lane holds s = m0 + w*32 + mt*16 + l15 (col index),
        // n = n0 + nt*16 + quad*4 + r (row index) -> 4 consecutive cols per quad
        bf16* base = (which == 0) ? Qb : Kb;
        #pragma unroll
        for (int nt = 0; nt < 8; nt++) {
            int n  = n0 + nt * 16 + quad * 4;
            int hh = (n >> 6) & 15, col = n & 63;
            #pragma unroll
            for (int mt = 0; mt < 2; mt++) {
                int s = m0 + w * 32 + mt * 16 + l15;
                uint2 o;
                o.x = pkrne(acc[mt][nt][0], acc[mt][nt][1]);
                o.y = pkrne(acc[mt][nt][2], acc[mt][nt][3]);
                *(uint2*)(base + ((size_t)hh * S_ + s) * 64 + col) = o;
            }
        }
    } else {
        // ---- V: normal orientation -> reg-quad = 4 consecutive s ----
        #pragma unroll 1
        for (int kt = 0; kt < 32; kt++) {
            const int cur = kt % 3;
            if (kt + 2 < 32) stage_ab((kt + 2) % 3, (kt + 2) * 32);
            bf16x8 a0 = ldsfrag32(&xa[cur][0], w * 32 + l15,      quad);
            bf16x8 a1 = ldsfrag32(&xa[cur][0], w * 32 + 16 + l15, quad);
            #pragma unroll
            for (int nt = 0; nt < 8; nt++) {
                bf16x8 b = ldsfrag32(&wb2[cur][0], nt * 16 + l15, quad);
                acc[0][nt] = MFMA16(a0, b, acc[0][nt]);
                acc[1][nt] = MFMA16(a1, b, acc[1][nt]);
            }
            if (kt + 1 < 32) {
                if (kt + 2 < 32) { WAITCNT_BAR(4); } else { WAITCNT_BAR(0); }
            }
        }
        #pragma unroll
        for (int nt = 0; nt < 8; nt++) {
            int n = n0 + nt * 16 + l15;
            int hh = (n >> 6) & 15, col = n & 63;
            #pragma unroll
            for (int mt = 0; mt < 2; mt++) {
                int s = m0 + w * 32 + mt * 16 + quad * 4;
                uint2 o;
                o.x = pkrne(acc[mt][nt][0], acc[mt][nt][1]);
                o.y = pkrne(acc[mt][nt][2], acc[mt][nt][3]);
                *(uint2*)(Vtb + ((size_t)hh * 64 + col) * S_ + s) = o;
            }
        }
    }
}

// ---------------------------------------------------------------------------
// Kernel 2: attention. R17/R19/R23 champion version exactly (83.2-83.9 µs).
// Session ledger: occupancy x2, L2 swizzle, setprio, VALU<->MFMA shift,
// counted-vmcnt, ILP-split — all null-to-negative on this structure; it
// sits at the plain-HIP 2-phase attention ceiling (~920 TF effective).
// ---------------------------------------------------------------------------
template<int NKT, bool FULL>
__global__ __attribute__((amdgpu_waves_per_eu(2))) __launch_bounds__(256)
void attn(const bf16* __restrict__ Qb, const bf16* __restrict__ Kb,
          const bf16* __restrict__ Vtb, bf16* __restrict__ Cat,
          bf16* __restrict__ Opart, float* __restrict__ lpart)
{
    // ---- XCD-aware bijective swizzle (x fastest in dispatch linearization)
    const int fid = blockIdx.x + 16 * (blockIdx.y + 16 * blockIdx.z);
    const int xcd = fid & 7, r = fid >> 3;
    const int hz  = (r >> 4) * 8 + xcd;
    const int m0   = (r & 15) * 256;
    const int h    = hz & 15;
    const int half = hz >> 4;
    const int keybase = half * (NKT * 64);

    __shared__ __align__(16) bf16 ka[2][64 * 64];   // 8 KB/buf, swizzled [key][dk]
    __shared__ __align__(16) bf16 vt[2][64 * 64];   // 8 KB/buf, swizzled [dv][key]

    const int t = threadIdx.x, lane = t & 63, w = t >> 6;
    const int l15 = lane & 15, quad = lane >> 4;

    auto stage_kv = [&](int buf, int key0) {
        const char* kg = (const char*)(Kb + ((size_t)h * S_ + key0) * 64);
        #pragma unroll
        for (int j = 0; j < 2; j++) {
            int c = (j * 4 + w) * 64 + lane;
            int row = c >> 3, ch = (c & 7) ^ (row & 7);
            stage16(kg + row * 128 + ch * 16, (char*)&ka[buf][0] + (j * 4 + w) * 1024);
        }
        const char* vg = (const char*)(Vtb + (size_t)h * 64 * S_ + key0);
        #pragma unroll
        for (int j = 0; j < 2; j++) {
            int c = (j * 4 + w) * 64 + lane;
            int row = c >> 3, ch = (c & 7) ^ (row & 7);
            stage16(vg + (size_t)row * (S_ * 2) + ch * 16, (char*)&vt[buf][0] + (j * 4 + w) * 1024);
        }
    };

    // Q fragments, loop-invariant, straight from global (B-side of K·Qᵀ).
    // Wave owns q-rows [m0 + w*64, m0 + w*64 + 64).
    bf16x8 qf[4][2];
    #pragma unroll
    for (int nq = 0; nq < 4; nq++)
        #pragma unroll
        for (int ks = 0; ks < 2; ks++)
            qf[nq][ks] = *(const bf16x8*)(Qb +
                ((size_t)h * S_ + m0 + w * 64 + nq * 16 + l15) * 64 + ks * 32 + quad * 8);

    // all-ones bf16 A fragment for row-sum MFMA
    bf16x8 ones8;
    #pragma unroll
    for (int i = 0; i < 8; i++) ones8[i] = (short)0x3F80;

    const floatx4 fz = {0.f, 0.f, 0.f, 0.f};
    floatx4 acc[4][4];          // acc[nq][nt]: Oᵀ[dv=nt*16+quad*4+r][q=l15 of nq-tile]
    floatx4 rsa[4];             // rsa[nq][r] all == rowsum for q=l15 of nq-tile
    #pragma unroll
    for (int nq = 0; nq < 4; nq++) {
        rsa[nq] = fz;
        #pragma unroll
        for (int nt = 0; nt < 4; nt++) acc[nq][nt] = fz;
    }

    stage_kv(0, keybase);
    __syncthreads();

    #pragma unroll 1
    for (int kt = 0; kt < NKT; kt++) {
        const int cur = kt & 1;
        if (kt + 1 < NKT) stage_kv(cur ^ 1, keybase + (kt + 1) * 64);

        // Sᵀ[key][q] = K·Qᵀ, exp2 + truncating pack, mk-by-mk to bound liveness
        union bf4u { bf16x4 v; unsigned int u[2]; };
        bf4u pf[4][4];
        #pragma unroll
        for (int mk = 0; mk < 4; mk++) {
            bf16x8 a0 = ldsfrag(&ka[cur][0], mk * 16 + l15, quad);
            bf16x8 a1 = ldsfrag(&ka[cur][0], mk * 16 + l15, 4 + quad);
            floatx4 s[4];
            #pragma unroll
            for (int nq = 0; nq < 4; nq++) s[nq] = fz;
            __builtin_amdgcn_s_setprio(1);
            #pragma unroll
            for (int nq = 0; nq < 4; nq++) s[nq] = MFMA16(a0, qf[nq][0], s[nq]);
            #pragma unroll
            for (int nq = 0; nq < 4; nq++) s[nq] = MFMA16(a1, qf[nq][1], s[nq]);
            __builtin_amdgcn_s_setprio(0);
            #pragma unroll
            for (int nq = 0; nq < 4; nq++) {
                float p0 = EXP2(s[nq][0]);
                float p1 = EXP2(s[nq][1]);
                float p2 = EXP2(s[nq][2]);
                float p3 = EXP2(s[nq][3]);
                pf[mk][nq].u[0] = pktrunc(p0, p1);
                pf[mk][nq].u[1] = pktrunc(p2, p3);
            }
        }

        // Oᵀ += Vᵀ·Pᵀ : per pair p of 16-key groups (32 keys per MFMA);
        // rowsums ride the MFMA pipe via ones-A.
        #pragma unroll
        for (int p = 0; p < 2; p++) {
            union { bf16x8 v8; bf16x4 v4[2]; } b8[4];
            #pragma unroll
            for (int nq = 0; nq < 4; nq++) {
                b8[nq].v4[0] = pf[2 * p + 0][nq].v;
                b8[nq].v4[1] = pf[2 * p + 1][nq].v;
            }
            __builtin_amdgcn_s_setprio(1);
            #pragma unroll
            for (int nq = 0; nq < 4; nq++)
                rsa[nq] = MFMA16(ones8, b8[nq].v8, rsa[nq]);
            __builtin_amdgcn_s_setprio(0);
            #pragma unroll
            for (int nt = 0; nt < 4; nt++) {
                const char* vb = (const char*)&vt[cur][0]
                               + (nt * 16 + l15) * 128 + (quad & 1) * 8;
                const int r7 = l15 & 7;            // row&7 for swizzle
                union { bf16x8 v8; bf16x4 v4[2]; } a8;
                a8.v4[0] = *(const bf16x4*)(vb + (((4 * p +     (quad >> 1)) ^ r7) << 4));
                a8.v4[1] = *(const bf16x4*)(vb + (((4 * p + 2 + (quad >> 1)) ^ r7) << 4));
                __builtin_amdgcn_s_setprio(1);
                #pragma unroll
                for (int nq = 0; nq < 4; nq++)
                    acc[nq][nt] = MFMA16(a8.v8, b8[nq].v8, acc[nq][nt]);
                __builtin_amdgcn_s_setprio(0);
            }
        }
        __syncthreads();   // staging(next) landed; all waves done with cur
    }

    if (FULL) {
        #pragma unroll
        for (int nq = 0; nq < 4; nq++) {
            float inv = 1.0f / rsa[nq][0];
            int q = m0 + w * 64 + nq * 16 + l15;
            #pragma unroll
            for (int nt = 0; nt < 4; nt++) {
                uint2 o;
                o.x = pktrunc(acc[nq][nt][0] * inv, acc[nq][nt][1] * inv);
                o.y = pktrunc(acc[nq][nt][2] * inv, acc[nq][nt][3] * inv);
                *(uint2*)(Cat + (size_t)q * (H_ * DV_) + h * 64 + nt * 16 + quad * 4) = o;
            }
        }
    } else {
        const size_t plane = (size_t)(half * H_ + h) * S_;
        #pragma unroll
        for (int nq = 0; nq < 4; nq++) {
            int q = m0 + w * 64 + nq * 16 + l15;
            #pragma unroll
            for (int nt = 0; nt < 4; nt++) {
                uint2 o;
                o.x = pktrunc(acc[nq][nt][0], acc[nq][nt][1]);
                o.y = pktrunc(acc[nq][nt][2], acc[nq][nt][3]);
                *(uint2*)(Opart + (plane + q) * 64 + nt * 16 + quad * 4) = o;
            }
            if (quad == 0) lpart[plane + q] = rsa[nq][0];
        }
    }
}

// ---------------------------------------------------------------------------
// Kernel 2b: combine NS bf16 key-split partials -> Cat bf16
// ---------------------------------------------------------------------------
template<int NS>
__global__ __launch_bounds__(256)
void combineN(const bf16* __restrict__ Opart, const float* __restrict__ lpart,
              bf16* __restrict__ Cat)
{
    const int h = blockIdx.y;
    const int off = (blockIdx.x * 256 + threadIdx.x) * 8;   // within [S*64]
    const int s = off >> 6, dv = off & 63;
    float a[8] = {0.f, 0.f, 0.f, 0.f, 0.f, 0.f, 0.f, 0.f};
    float l = 0.f;
    #pragma unroll
    for (int p = 0; p < NS; p++) {
        union { bf16x8 v; bf16 e[8]; } o;
        o.v = *(const bf16x8*)(Opart + (size_t)(p * H_ + h) * S_ * 64 + off);
        #pragma unroll
        for (int i = 0; i < 8; i++) a[i] += bf2f(o.e[i]);
        l += lpart[(size_t)(p * H_ + h) * S_ + s];
    }
    float inv = 1.0f / l;
    uint4 o;
    o.x = pktrunc(a[0] * inv, a[1] * inv);
    o.y = pktrunc(a[2] * inv, a[3] * inv);
    o.z = pktrunc(a[4] * inv, a[5] * inv);
    o.w = pktrunc(a[6] * inv, a[7] * inv);
    *(uint4*)(Cat + (size_t)s * (H_ * DV_) + h * 64 + dv) = o;
}

// ---------------------------------------------------------------------------
// Kernel 3: output projection, 128x64 tiles, BK=64, 3-deep counted-vmcnt
// ring (R23 champion version).
// ---------------------------------------------------------------------------
__global__ __launch_bounds__(256)
void out_proj(const bf16* __restrict__ Cat, const bf16* __restrict__ Wct,
              const float* __restrict__ bc, float* __restrict__ out)
{
    const int fid = blockIdx.x + 32 * blockIdx.y;      // x fastest
    const int lin = (fid & 7) * 64 + (fid >> 3);       // bijective: 512 = 8*64
    const int m0 = (lin & 31) * 128;
    const int n0 = (lin >> 5) * 64;
    __shared__ __align__(16) bf16 ca[3][128 * 64];   // 16 KB/buf
    __shared__ __align__(16) bf16 wb2[3][64 * 64];   // 8 KB/buf

    const int t = threadIdx.x, lane = t & 63, w = t >> 6;
    const int l15 = lane & 15, quad = lane >> 4;

    // 4+2 = 6 stage16 per thread per tile
    auto stage_ab = [&](int buf, int kk) {
        #pragma unroll
        for (int j = 0; j < 4; j++) {
            int idx = j * 256 + t;
            int r = idx >> 3, c = idx & 7;
            int ch = c ^ (r & 7);
            stage16((const char*)Cat + ((size_t)(m0 + r) * D_ + kk + ch * 8) * 2,
                    (char*)&ca[buf][0] + (j * 4 + w) * 1024);
        }
        #pragma unroll
        for (int j = 0; j < 2; j++) {
            int idx = j * 256 + t;
            int r = idx >> 3, c = idx & 7;
            int ch = c ^ (r & 7);
            stage16((const char*)Wct + ((size_t)(n0 + r) * D_ + kk + ch * 8) * 2,
                    (char*)&wb2[buf][0] + (j * 4 + w) * 1024);
        }
    };

    const floatx4 fz = {0.f, 0.f, 0.f, 0.f};
    floatx4 acc[2][4];
    #pragma unroll
    for (int mt = 0; mt < 2; mt++)
        #pragma unroll
        for (int nt = 0; nt < 4; nt++) acc[mt][nt] = fz;

    // prologue: 2 tiles in flight, counted wait for tile 0 only
    stage_ab(0, 0);
    stage_ab(1, 64);
    WAITCNT_BAR(6);

    #pragma unroll 1
    for (int kt = 0; kt < 16; kt++) {
        const int cur = kt % 3;
        if (kt + 2 < 16) stage_ab((kt + 2) % 3, (kt + 2) * 64);
        #pragma unroll
        for (int ks = 0; ks < 2; ks++) {
            bf16x8 a0 = ldsfrag(&ca[cur][0], w * 32 + l15,      ks * 4 + quad);
            bf16x8 a1 = ldsfrag(&ca[cur][0], w * 32 + 16 + l15, ks * 4 + quad);
            #pragma unroll
            for (int nt = 0; nt < 4; nt++) {
                bf16x8 b = ldsfrag(&wb2[cur][0], nt * 16 + l15, ks * 4 + quad);
                acc[0][nt] = MFMA16(a0, b, acc[0][nt]);
                acc[1][nt] = MFMA16(a1, b, acc[1][nt]);
            }
        }
        if (kt + 1 < 16) {
            if (kt + 2 < 16) { WAITCNT_BAR(6); } else { WAITCNT_BAR(0); }
        }
    }

    #pragma unroll
    for (int nt = 0; nt < 4; nt++) {
        int col = n0 + nt * 16 + l15;
        float bias = bc[col];
        #pragma unroll
        for (int mt = 0; mt < 2; mt++)
            #pragma unroll
            for (int r = 0; r < 4; r++) {
                int row = m0 + w * 32 + mt * 16 + quad * 4 + r;
                out[(size_t)row * D_ + col] = acc[mt][nt][r] + bias;
            }
    }
}

extern "C" void kernel_launch(void* const* d_in, const int* in_sizes, int n_in,
                              void* d_out, int out_size, void* d_ws, size_t ws_size,
                              hipStream_t stream)
{
    const float* x  = (const float*)d_in[0];
    const float* Wq = (const float*)d_in[1];
    const float* Wk = (const float*)d_in[2];
    const float* Wv = (const float*)d_in[3];
    const float* Wc = (const float*)d_in[4];
    const float* bc = (const float*)d_in[5];
    float* out = (float*)d_out;

    bf16* xb  = (bf16*)d_ws;                          // [S][D] 8MB, aliased as Cat
    bf16* Cat = xb;
    bf16* Wt  = xb  + (size_t)S_ * D_;                // [3072][1024] 6MB
    bf16* Wct = Wt  + (size_t)3 * H_ * 64 * D_;       // [1024][1024] 2MB
    bf16* Qb  = Wct + (size_t)D_ * H_ * DV_;          // [H][S][64]  8MB
    bf16* Kb  = Qb  + (size_t)H_ * S_ * 64;           // [H][S][64]  8MB
    bf16* Vtb = Kb  + (size_t)H_ * S_ * 64;           // [H][64][S]  8MB
    bf16* Opart = Vtb + (size_t)H_ * 64 * S_;         // [NS][H][S][64] bf16, NS*8MB

    // lpart sits after however many Opart planes the chosen split uses
    float* lpart4 = (float*)(Opart + (size_t)4 * H_ * S_ * 64);  // [4][H][S]
    float* lpart2 = (float*)(Opart + (size_t)2 * H_ * S_ * 64);  // [2][H][S]
    const size_t need4 = (size_t)((char*)(lpart4 + (size_t)4 * H_ * S_) - (char*)d_ws);
    const size_t need2 = (size_t)((char*)(lpart2 + (size_t)2 * H_ * S_) - (char*)d_ws);

    prep<<<dim3(3072), 256, 0, stream>>>(x, Wq, Wk, Wv, Wc, xb, Wt, Wct);
    qkv_gemm<<<dim3(S_ / 128, 3072 / 128), 256, 0, stream>>>(xb, Wt, Qb, Kb, Vtb);

    if (ws_size >= need4) {
        attn<16, false><<<dim3(16, 16, 4), 256, 0, stream>>>(
            Qb, Kb, Vtb, Cat, Opart, lpart4);
        combineN<4><<<dim3(S_ * 64 / 2048, H_), 256, 0, stream>>>(Opart, lpart4, Cat);
    } else if (ws_size >= need2) {
        attn<32, false><<<dim3(16, 16, 2), 256, 0, stream>>>(
            Qb, Kb, Vtb, Cat, Opart, lpart2);
        combineN<2><<<dim3(S_ * 64 / 2048, H_), 256, 0, stream>>>(Opart, lpart2, Cat);
    } else {
        attn<64, true><<<dim3(16, 16, 1), 256, 0, stream>>>(
            Qb, Kb, Vtb, Cat, Opart, lpart2);
    }

    out_proj<<<dim3(S_ / 128, D_ / 64), 256, 0, stream>>>(Cat, Wct, bc, out);
}